// Round 11
// baseline (18517.232 us; speedup 1.0000x reference)
//
#include <hip/hip_runtime.h>
#include <math.h>

static constexpr int NB  = 1024;
static constexpr int NS  = 100;
static constexpr int NH  = 128;
static constexpr int GPB = 2;           // batches per block
static constexpr int NTHR = 256;
static constexpr int NBLK = NB / GPB;   // 512 blocks, 2/CU
static constexpr int CH  = 4;           // chunk (timesteps per bulk)

static constexpr int OUT_MU = 0;
static constexpr int OUT_LV = NB * NS;
static constexpr int OUT_Z  = 2 * NB * NS;
static constexpr int OUT_TI = 3 * NB * NS;
static constexpr int OUT_LP = 4 * NB * NS;

#define NEGF (-3.4e38f)

// 3-row x 1-batch f32 dot — each accumulator's fmaf chain is k-ascending,
// bitwise identical to dot2x3f's per-accumulator chains (v14/v19-verified class).
template<int C4>
__device__ __forceinline__ void dot1x3f(const float* __restrict__ wr0,
        const float* __restrict__ wr1, const float* __restrict__ wr2,
        const float* __restrict__ x, float& r0, float& r1, float& r2)
{
    const float4* W0 = reinterpret_cast<const float4*>(wr0);
    const float4* W1 = reinterpret_cast<const float4*>(wr1);
    const float4* W2 = reinterpret_cast<const float4*>(wr2);
    const float4* X  = reinterpret_cast<const float4*>(x);
    float a0 = 0.f, a1 = 0.f, a2 = 0.f;
    #pragma unroll 4
    for (int c = 0; c < C4; ++c) {
        float4 u0 = W0[c], u1 = W1[c], u2 = W2[c];
        float4 v = X[c];
        a0 = fmaf(u0.x, v.x, a0); a0 = fmaf(u0.y, v.y, a0); a0 = fmaf(u0.z, v.z, a0); a0 = fmaf(u0.w, v.w, a0);
        a1 = fmaf(u1.x, v.x, a1); a1 = fmaf(u1.y, v.y, a1); a1 = fmaf(u1.z, v.z, a1); a1 = fmaf(u1.w, v.w, a1);
        a2 = fmaf(u2.x, v.x, a2); a2 = fmaf(u2.y, v.y, a2); a2 = fmaf(u2.z, v.z, a2); a2 = fmaf(u2.w, v.w, a2);
    }
    r0 = a0; r1 = a1; r2 = a2;
}

// One weight row vs TWO LDS vectors — v14 verbatim per-accumulator chain.
template<int C4>
__device__ __forceinline__ void dot2f(const float* __restrict__ w,
        const float* __restrict__ x0, const float* __restrict__ x1, float& r0, float& r1)
{
    const float4* W = reinterpret_cast<const float4*>(w);
    const float4* X0 = reinterpret_cast<const float4*>(x0);
    const float4* X1 = reinterpret_cast<const float4*>(x1);
    float a0 = 0.f, a1 = 0.f;
    #pragma unroll 8
    for (int c = 0; c < C4; ++c) {
        float4 u = W[c];
        float4 v0 = X0[c], v1 = X1[c];
        a0 = fmaf(u.x, v0.x, a0); a0 = fmaf(u.y, v0.y, a0); a0 = fmaf(u.z, v0.z, a0); a0 = fmaf(u.w, v0.w, a0);
        a1 = fmaf(u.x, v1.x, a1); a1 = fmaf(u.y, v1.y, a1); a1 = fmaf(u.z, v1.z, a1); a1 = fmaf(u.w, v1.w, a1);
    }
    r0 = a0; r1 = a1;
}

// f64-accum dot (mu/lv epilogue) — R9 verbatim.
template<int C4>
__device__ __forceinline__ double dotwd(const float* __restrict__ w, const float* __restrict__ x)
{
    const float4* W = reinterpret_cast<const float4*>(w);
    double a = 0.0;
    #pragma unroll 8
    for (int c = 0; c < C4; ++c) {
        float4 u = W[c];
        const float* p = x + 4 * c;
        a = fma((double)u.x, (double)p[0], a);
        a = fma((double)u.y, (double)p[1], a);
        a = fma((double)u.z, (double)p[2], a);
        a = fma((double)u.w, (double)p[3], a);
    }
    return a;
}

// GRU nonlinearity on register gate-partials — identical expression to gruc
// (HW-verified in v19, absmax pinned).
__device__ __forceinline__ float grucr(const float* __restrict__ bih, const float* __restrict__ bhh,
        float pa0, float pa1, float pa2, float pb0, float pb1, float pb2, float hold, int j)
{
    double r = 1.0 / (1.0 + exp(-(((double)pa0 + (double)bih[j])      + ((double)pb0 + (double)bhh[j]))));
    double z = 1.0 / (1.0 + exp(-(((double)pa1 + (double)bih[NH + j]) + ((double)pb1 + (double)bhh[NH + j]))));
    double n = tanh(((double)pa2 + (double)bih[2*NH + j]) + r * ((double)pb2 + (double)bhh[2*NH + j]));
    return (float)((1.0 - z) * n + z * (double)hold);
}

// q half-chain (v14-verbatim; HW-verified v19/v20/v21).
__device__ __forceinline__ void qhalf(const float* __restrict__ col, int k0,
        const float* __restrict__ hA, const float* __restrict__ hB, double& r0, double& r1)
{
    double a00=0.0,a01=0.0,a02=0.0,a03=0.0;
    double a10=0.0,a11=0.0,a12=0.0,a13=0.0;
    #pragma unroll 8
    for (int k = 0; k < 64; k += 4) {
        float w0 = col[(size_t)(k0+k+0) * NH];
        float w1 = col[(size_t)(k0+k+1) * NH];
        float w2 = col[(size_t)(k0+k+2) * NH];
        float w3 = col[(size_t)(k0+k+3) * NH];
        float4 h0 = *reinterpret_cast<const float4*>(&hA[k0+k]);
        float4 h1v = *reinterpret_cast<const float4*>(&hB[k0+k]);
        a00 = fma((double)w0, (double)h0.x, a00);
        a01 = fma((double)w1, (double)h0.y, a01);
        a02 = fma((double)w2, (double)h0.z, a02);
        a03 = fma((double)w3, (double)h0.w, a03);
        a10 = fma((double)w0, (double)h1v.x, a10);
        a11 = fma((double)w1, (double)h1v.y, a11);
        a12 = fma((double)w2, (double)h1v.z, a12);
        a13 = fma((double)w3, (double)h1v.w, a13);
    }
    r0 = (a00+a01)+(a02+a03); r1 = (a10+a11)+(a12+a13);
}

// relu head (v14-verbatim chain; HW-verified v19/v20/v21). qh pre-combined.
__device__ __forceinline__ float relu_head(const double* __restrict__ qh,
        const double2* __restrict__ dA, const float* __restrict__ va, float c0v, float c1v)
{
    double c00 = (double)c0v, c10 = (double)c1v;
    double acc0=0.0,acc1=0.0,acc2=0.0,acc3=0.0;
    #pragma unroll 4
    for (int h = 0; h < NH; h += 4) {
        double2 A0=dA[h+0],A1=dA[h+1],A2=dA[h+2],A3=dA[h+3];
        double p0 = fma(c00,A0.x,fma(c10,A0.y,qh[h+0]));
        double p1 = fma(c00,A1.x,fma(c10,A1.y,qh[h+1]));
        double p2 = fma(c00,A2.x,fma(c10,A2.y,qh[h+2]));
        double p3 = fma(c00,A3.x,fma(c10,A3.y,qh[h+3]));
        acc0 = fma(fmax(p0,0.0),(double)va[h+0],acc0);
        acc1 = fma(fmax(p1,0.0),(double)va[h+1],acc1);
        acc2 = fma(fmax(p2,0.0),(double)va[h+2],acc2);
        acc3 = fma(fmax(p3,0.0),(double)va[h+3],acc3);
    }
    return (float)((acc0+acc1)+(acc2+acc3));
}

// tanh head (v14-verbatim chain; HW-verified v19/v20/v21).
__device__ __forceinline__ float tanh_head(const double* __restrict__ qh,
        const double2* __restrict__ dA, const float* __restrict__ vp, float c0v, float c1v)
{
    double c00 = (double)c0v, c10 = (double)c1v;
    double acc0=0.0,acc1=0.0,acc2=0.0,acc3=0.0;
    #pragma unroll 4
    for (int h = 0; h < NH; h += 4) {
        double2 A0=dA[h+0],A1=dA[h+1],A2=dA[h+2],A3=dA[h+3];
        double p0 = fma(c00,A0.x,fma(c10,A0.y,qh[h+0]));
        double p1 = fma(c00,A1.x,fma(c10,A1.y,qh[h+1]));
        double p2 = fma(c00,A2.x,fma(c10,A2.y,qh[h+2]));
        double p3 = fma(c00,A3.x,fma(c10,A3.y,qh[h+3]));
        acc0 = fma((double)tanhf((float)p0),(double)vp[h+0],acc0);
        acc1 = fma((double)tanhf((float)p1),(double)vp[h+1],acc1);
        acc2 = fma((double)tanhf((float)p2),(double)vp[h+2],acc2);
        acc3 = fma((double)tanhf((float)p3),(double)vp[h+3],acc3);
    }
    return (float)((acc0+acc1)+(acc2+acc3));
}

// context chain (v14-verbatim; HW-verified v19/v20/v21).
__device__ __forceinline__ float ctx_chain(const float* __restrict__ a,
        const float* __restrict__ c0, const float* __restrict__ c1,
        float w0, float w1, float bb)
{
    double a0=0.0,a1=0.0,a2=0.0,a3=0.0;
    #pragma unroll 5
    for (int s = 0; s < NS; s += 4) {
        float ih0 = fmaf(c0[s+0], w0, fmaf(c1[s+0], w1, bb));
        float ih1 = fmaf(c0[s+1], w0, fmaf(c1[s+1], w1, bb));
        float ih2 = fmaf(c0[s+2], w0, fmaf(c1[s+2], w1, bb));
        float ih3 = fmaf(c0[s+3], w0, fmaf(c1[s+3], w1, bb));
        a0 += (double)a[s+0] * (double)ih0;
        a1 += (double)a[s+1] * (double)ih1;
        a2 += (double)a[s+2] * (double)ih2;
        a3 += (double)a[s+3] * (double)ih3;
    }
    return (float)((a0+a1)+(a2+a3));
}

__global__ __launch_bounds__(NTHR) void vae_v22(
    const float* __restrict__ instance, const int* __restrict__ sol1,
    const int* __restrict__ sol2, const float* __restrict__ eps,
    const float* __restrict__ emb_i_W, const float* __restrict__ emb_i_b,
    const float* __restrict__ emb_r_W, const float* __restrict__ emb_r_b,
    const float* __restrict__ attn_W, const float* __restrict__ attn_v,
    const float* __restrict__ gru_Wih, const float* __restrict__ gru_Whh,
    const float* __restrict__ gru_bih, const float* __restrict__ gru_bhh,
    const float* __restrict__ grud_Wih, const float* __restrict__ grud_Whh,
    const float* __restrict__ grud_bih, const float* __restrict__ grud_bhh,
    const float* __restrict__ efc1_W, const float* __restrict__ efc1_b,
    const float* __restrict__ efc2_W, const float* __restrict__ efc2_b,
    const float* __restrict__ ptr_W, const float* __restrict__ ptr_v,
    const float* __restrict__ pfc1_W, const float* __restrict__ pfc1_b,
    const float* __restrict__ pfc2_W, const float* __restrict__ pfc2_b,
    float* __restrict__ out)
{
    __shared__ __align__(16) float  s_x[GPB][360];          // Z kept at [128..227] for decoder
    __shared__ __align__(16) float  s_h1[GPB][NH], s_h2[GPB][NH];
    __shared__ double2 dAa[NH], dAp[NH];
    __shared__ double dAba[NH], dAbp[NH];
    __shared__ float  s_c0[GPB][NS], s_c1[GPB][NS];
    __shared__ float  t_wi0[NH], t_wi1[NH], t_bi[NH];
    __shared__ float  t_wr0[NH], t_wr1[NH], t_br[NH];
    __shared__ float  t_va[NH], t_vp[NH];
    __shared__ float  t_gbih[3*NH], t_gbhh[3*NH], t_dbih[3*NH], t_dbhh[3*NH];
    __shared__ float  t_p1b[256], t_p2b[NH];
    __shared__ int    s_sol1[GPB][NS], s_sol2[GPB][NS];
    // ---- chunk scratch ----
    __shared__ __align__(16) float  refs[CH][GPB][NH];      // precomputed GRU1 x-inputs
    __shared__ __align__(16) float  h1buf[CH][GPB][NH];     // h1 snapshots / h2 ping-pong
    __shared__ float    rcb0[GPB][CH+1], rcb1[GPB][CH+1];
    __shared__ unsigned maskb[CH][GPB][4], m_run[GPB][4];
    __shared__ __align__(16) double d_qh[CH][GPB][NH];
    __shared__ __align__(16) float  d_pl[2*CH][NS];
    __shared__ __align__(16) float  d_x[2*CH][360];
    __shared__ __align__(16) float  d_fch[2*CH][256];
    __shared__ __align__(16) float  d_fco[CH][GPB][NH];

    const int tid = threadIdx.x;
    const int bbase = blockIdx.x * GPB;
    const int j = tid & (NH - 1);
    const int half = tid >> 7;
    const int g = half;
    const int lane = tid & 63;

    // ---------- init (v21 verbatim) ----------
    if (tid < NH) {
        t_wi0[tid] = emb_i_W[2*tid]; t_wi1[tid] = emb_i_W[2*tid+1]; t_bi[tid] = emb_i_b[tid];
        t_wr0[tid] = emb_r_W[2*tid]; t_wr1[tid] = emb_r_W[2*tid+1]; t_br[tid] = emb_r_b[tid];
        t_va[tid] = attn_v[tid]; t_vp[tid] = ptr_v[tid];
        t_p2b[tid] = pfc2_b[tid];
    }
    t_p1b[tid] = pfc1_b[tid];
    for (int i = tid; i < 3 * NH; i += NTHR) {
        t_gbih[i] = gru_bih[i]; t_gbhh[i] = gru_bhh[i];
        t_dbih[i] = grud_bih[i]; t_dbhh[i] = grud_bhh[i];
    }
    for (int i = tid; i < GPB * NS; i += NTHR) {
        int gg = i / NS, s = i - gg * NS;
        s_c0[gg][s] = instance[(size_t)((bbase + gg) * NS + s) * 2 + 0];
        s_c1[gg][s] = instance[(size_t)((bbase + gg) * NS + s) * 2 + 1];
        s_sol1[gg][s] = sol1[(bbase + gg) * NS + s];
        s_sol2[gg][s] = sol2[(bbase + gg) * NS + s];
    }
    s_h1[g][j] = 0.f;
    s_h2[g][j] = 0.f;
    __syncthreads();
    {   // collapse tables (R9 verbatim)
        const float* Wm = (half == 0) ? attn_W : ptr_W;
        double a0 = 0.0, a1 = 0.0, ab = 0.0;
        for (int k = 0; k < NH; ++k) {
            double wv2 = (double)Wm[(size_t)k * NH + j];
            a0 = fma((double)t_wi0[k], wv2, a0);
            a1 = fma((double)t_wi1[k], wv2, a1);
            ab = fma((double)t_bi[k],  wv2, ab);
        }
        if (half == 0) { dAa[j].x = a0; dAa[j].y = a1; dAba[j] = ab; }
        else           { dAp[j].x = a0; dAp[j].y = a1; dAbp[j] = ab; }
    }
    __syncthreads();

    // ---------- encoder: chunked; single-phase in-register GRU steps ----------
    for (int c = 0; c < (NS - 1 + CH - 1) / CH; ++c) {
        const int t0 = 1 + c * CH;
        const int CHc = (t0 + CH <= NS) ? CH : (NS - t0);
        // pre: rcb (GRUd ref coords, sol1[t0+qi]) + refs (GRU1 x-inputs, sol1[t0+q-1])
        if (tid < GPB) {
            const int gg = tid;
            for (int qi = 0; qi < CHc; ++qi) {
                int sp = s_sol1[gg][t0 + qi];
                rcb0[gg][qi] = s_c0[gg][sp];
                rcb1[gg][qi] = s_c1[gg][sp];
            }
        }
        for (int idx = tid; idx < CHc * GPB * NH; idx += NTHR) {
            int q = idx >> 8, r = idx & 255, gg = r >> 7, jj = r & 127;
            int sp = s_sol1[gg][t0 + q - 1];
            refs[q][gg][jj] = fmaf(s_c0[gg][sp], t_wr0[jj], fmaf(s_c1[gg][sp], t_wr1[jj], t_br[jj]));
        }
        __syncthreads();
        // ---- E1: h1 serial, ONE phase/step (in-register gates; chains identical) ----
        for (int q = 0; q < CHc; ++q) {
            const float* h1src = (q == 0) ? s_h1[g] : h1buf[q-1][g];
            float pa0, pa1, pa2, pb0, pb1, pb2;
            dot1x3f<32>(gru_Wih + (size_t)j * NH, gru_Wih + (size_t)(NH + j) * NH,
                        gru_Wih + (size_t)(2*NH + j) * NH, refs[q][g], pa0, pa1, pa2);
            dot1x3f<32>(gru_Whh + (size_t)j * NH, gru_Whh + (size_t)(NH + j) * NH,
                        gru_Whh + (size_t)(2*NH + j) * NH, h1src, pb0, pb1, pb2);
            float hn = grucr(t_gbih, t_gbhh, pa0, pa1, pa2, pb0, pb1, pb2, h1src[j], j);
            h1buf[q][g][j] = hn;
            if (q == CHc - 1) s_h1[g][j] = hn;
            __syncthreads();
        }
        // ---- P1: q (attn) bulk — v21 verbatim ----
        {
            const float* col = attn_W + (size_t)NH * NH + j;
            for (int tt = (tid >> 7); tt < CHc; tt += 2) {
                double qA0, qA1, qB0, qB1;
                qhalf(col, 0,  h1buf[tt][0], h1buf[tt][1], qA0, qA1);
                qhalf(col, 64, h1buf[tt][0], h1buf[tt][1], qB0, qB1);
                d_qh[tt][0][j] = dAba[j] + (qA0 + qB0);
                d_qh[tt][1][j] = dAba[j] + (qA1 + qB1);
            }
        }
        __syncthreads();
        // ---- P2: relu heads bulk — v21 verbatim ----
        for (int idx = tid; idx < 2 * CHc * NS; idx += NTHR) {
            int task = idx / NS, s = idx - task * NS;
            int tt = task >> 1, gg = task & 1;
            d_pl[task][s] = relu_head(d_qh[tt][gg], dAa, t_va, s_c0[gg][s], s_c1[gg][s]);
        }
        __syncthreads();
        // ---- P3: softmax1 bulk — v21 verbatim ----
        {
            int w = tid >> 6;
            for (int task = w; task < 2 * CHc; task += 4) {
                float v1 = d_pl[task][lane];
                bool hasHi = (lane + 64 < NS);
                float v2 = hasHi ? d_pl[task][lane + 64] : NEGF;
                float m = fmaxf(v1, v2);
                m = fmaxf(m, __shfl_xor(m, 32)); m = fmaxf(m, __shfl_xor(m, 16));
                m = fmaxf(m, __shfl_xor(m, 8));  m = fmaxf(m, __shfl_xor(m, 4));
                m = fmaxf(m, __shfl_xor(m, 2));  m = fmaxf(m, __shfl_xor(m, 1));
                float f1 = (float)exp((double)v1 - (double)m);
                float f2 = 0.f;
                if (hasHi) f2 = (float)exp((double)v2 - (double)m);
                double ps = (double)f1 + (double)f2;
                ps += __shfl_xor(ps, 32); ps += __shfl_xor(ps, 16);
                ps += __shfl_xor(ps, 8);  ps += __shfl_xor(ps, 4);
                ps += __shfl_xor(ps, 2);  ps += __shfl_xor(ps, 1);
                d_pl[task][lane] = (float)((double)f1 / ps);
                if (hasHi) d_pl[task][lane + 64] = (float)((double)f2 / ps);
            }
        }
        __syncthreads();
        // ---- P4: ctx + new-ref into d_x — v21 verbatim ----
        for (int idx = tid; idx < 2 * CHc * NH; idx += NTHR) {
            int task = idx >> 7, jj = idx & 127;
            int tt = task >> 1, gg = task & 1;
            d_x[task][NH + jj] = ctx_chain(d_pl[task], s_c0[gg], s_c1[gg], t_wi0[jj], t_wi1[jj], t_bi[jj]);
            d_x[task][jj] = fmaf(rcb0[gg][tt], t_wr0[jj], fmaf(rcb1[gg][tt], t_wr1[jj], t_br[jj]));
        }
        __syncthreads();
        // ---- E2: h2 serial, ONE phase/step (in-register gates; h1buf = h2 ping-pong) ----
        for (int q = 0; q < CHc; ++q) {
            const float* h2src = (q == 0) ? s_h2[g] : h1buf[q-1][g];
            float pa0, pa1, pa2, pb0, pb1, pb2;
            dot1x3f<64>(grud_Wih + (size_t)j * 256, grud_Wih + (size_t)(NH + j) * 256,
                        grud_Wih + (size_t)(2*NH + j) * 256, d_x[2*q + g], pa0, pa1, pa2);
            dot1x3f<32>(grud_Whh + (size_t)j * NH, grud_Whh + (size_t)(NH + j) * NH,
                        grud_Whh + (size_t)(2*NH + j) * NH, h2src, pb0, pb1, pb2);
            float hn = grucr(t_dbih, t_dbhh, pa0, pa1, pa2, pb0, pb1, pb2, h2src[j], j);
            if (q == CHc - 1) s_h2[g][j] = hn; else h1buf[q][g][j] = hn;
            __syncthreads();
        }
    }

    // ---------- epilogue: mu, lv, Z (R9 verbatim) ----------
    for (int idx = tid; idx < GPB * NS; idx += NTHR) {
        int gg = idx / NS, s = idx - gg * NS, b = bbase + gg;
        double mu = dotwd<32>(efc1_W + (size_t)s * NH, s_h2[gg]) + (double)efc1_b[s];
        double lv = dotwd<32>(efc2_W + (size_t)s * NH, s_h2[gg]) + (double)efc2_b[s];
        double z  = mu + (double)eps[(size_t)b * NS + s] * exp(0.5 * lv);
        out[OUT_MU + b * NS + s] = (float)mu;
        out[OUT_LV + b * NS + s] = (float)lv;
        out[OUT_Z  + b * NS + s] = (float)z;
        s_x[gg][NH + s] = (float)z;   // Z slot [128..227], preserved through decoder
    }
    s_h1[g][j] = 0.f;
    __syncthreads();
    if (tid < GPB) {   // mask bitmap init (v15-verified) + TI[0]
        int b = bbase + tid;
        int s0 = s_sol2[tid][0];
        m_run[tid][0] = 0xFFFFFFFFu; m_run[tid][1] = 0xFFFFFFFFu;
        m_run[tid][2] = 0xFFFFFFFFu; m_run[tid][3] = 0xFu;
        m_run[tid][s0 >> 5] &= ~(1u << (s0 & 31));
        out[OUT_TI + b * NS + 0] = (float)s0;
    }
    __syncthreads();

    // ---------- decoder: single-phase D1 + v21 bulk ----------
    for (int c = 0; c < (NS - 1 + CH - 1) / CH; ++c) {
        const int t0 = 1 + c * CH;
        const int CHc = (t0 + CH <= NS) ? CH : (NS - t0);
        // pre-phase: mask snapshots + ref coords (v15-verified) + refs fill
        if (tid < GPB) {
            const int gg = tid;
            for (int qi = 0; qi <= CHc; ++qi) {
                int tt = t0 + qi;
                if (qi < CHc) {
                    maskb[qi][gg][0] = m_run[gg][0];
                    maskb[qi][gg][1] = m_run[gg][1];
                    maskb[qi][gg][2] = m_run[gg][2];
                    maskb[qi][gg][3] = m_run[gg][3];
                    int pt = s_sol2[gg][tt];
                    m_run[gg][pt >> 5] &= ~(1u << (pt & 31));
                }
                int sp = s_sol2[gg][tt - 1];
                rcb0[gg][qi] = s_c0[gg][sp];
                rcb1[gg][qi] = s_c1[gg][sp];
            }
        }
        for (int idx = tid; idx < CHc * GPB * NH; idx += NTHR) {
            int q = idx >> 8, r = idx & 255, gg = r >> 7, jj = r & 127;
            int sp = s_sol2[gg][t0 + q - 1];
            refs[q][gg][jj] = fmaf(s_c0[gg][sp], t_wr0[jj], fmaf(s_c1[gg][sp], t_wr1[jj], t_br[jj]));
        }
        __syncthreads();
        // ---- D1: serial GRU1, ONE phase/step ----
        for (int q = 0; q < CHc; ++q) {
            const float* h1src = (q == 0) ? s_h1[g] : h1buf[q-1][g];
            float pa0, pa1, pa2, pb0, pb1, pb2;
            dot1x3f<32>(gru_Wih + (size_t)j * NH, gru_Wih + (size_t)(NH + j) * NH,
                        gru_Wih + (size_t)(2*NH + j) * NH, refs[q][g], pa0, pa1, pa2);
            dot1x3f<32>(gru_Whh + (size_t)j * NH, gru_Whh + (size_t)(NH + j) * NH,
                        gru_Whh + (size_t)(2*NH + j) * NH, h1src, pb0, pb1, pb2);
            float hn = grucr(t_gbih, t_gbhh, pa0, pa1, pa2, pb0, pb1, pb2, h1src[j], j);
            h1buf[q][g][j] = hn;
            if (q == CHc - 1) s_h1[g][j] = hn;
            __syncthreads();
        }
        // ---- P1: q (attn) — v21 verbatim ----
        {
            const float* col = attn_W + (size_t)NH * NH + j;
            for (int tt = (tid >> 7); tt < CHc; tt += 2) {
                double qA0, qA1, qB0, qB1;
                qhalf(col, 0,  h1buf[tt][0], h1buf[tt][1], qA0, qA1);
                qhalf(col, 64, h1buf[tt][0], h1buf[tt][1], qB0, qB1);
                d_qh[tt][0][j] = dAba[j] + (qA0 + qB0);
                d_qh[tt][1][j] = dAba[j] + (qA1 + qB1);
            }
        }
        __syncthreads();
        // ---- P2: relu heads — v21 verbatim ----
        for (int idx = tid; idx < 2 * CHc * NS; idx += NTHR) {
            int task = idx / NS, s = idx - task * NS;
            int tt = task >> 1, gg = task & 1;
            d_pl[task][s] = relu_head(d_qh[tt][gg], dAa, t_va, s_c0[gg][s], s_c1[gg][s]);
        }
        __syncthreads();
        // ---- P3: softmax1 — v21 verbatim ----
        {
            int w = tid >> 6;
            for (int task = w; task < 2 * CHc; task += 4) {
                float v1 = d_pl[task][lane];
                bool hasHi = (lane + 64 < NS);
                float v2 = hasHi ? d_pl[task][lane + 64] : NEGF;
                float m = fmaxf(v1, v2);
                m = fmaxf(m, __shfl_xor(m, 32)); m = fmaxf(m, __shfl_xor(m, 16));
                m = fmaxf(m, __shfl_xor(m, 8));  m = fmaxf(m, __shfl_xor(m, 4));
                m = fmaxf(m, __shfl_xor(m, 2));  m = fmaxf(m, __shfl_xor(m, 1));
                float f1 = (float)exp((double)v1 - (double)m);
                float f2 = 0.f;
                if (hasHi) f2 = (float)exp((double)v2 - (double)m);
                double ps = (double)f1 + (double)f2;
                ps += __shfl_xor(ps, 32); ps += __shfl_xor(ps, 16);
                ps += __shfl_xor(ps, 8);  ps += __shfl_xor(ps, 4);
                ps += __shfl_xor(ps, 2);  ps += __shfl_xor(ps, 1);
                d_pl[task][lane] = (float)((double)f1 / ps);
                if (hasHi) d_pl[task][lane + 64] = (float)((double)f2 / ps);
            }
        }
        __syncthreads();
        // ---- P4: context + Z copy + ref into d_x — v21 verbatim ----
        for (int idx = tid; idx < 2 * CHc * NH; idx += NTHR) {
            int task = idx >> 7, jj = idx & 127;
            int tt = task >> 1, gg = task & 1;
            d_x[task][jj] = ctx_chain(d_pl[task], s_c0[gg], s_c1[gg], t_wi0[jj], t_wi1[jj], t_bi[jj]);
            float rc0 = rcb0[gg][tt], rc1 = rcb1[gg][tt];
            d_x[task][228 + jj] = fmaf(rc0, t_wr0[jj], fmaf(rc1, t_wr1[jj], t_br[jj]));
        }
        for (int idx = tid; idx < 2 * CHc * NS; idx += NTHR) {
            int task = idx / NS, s = idx - task * NS;
            int gg = task & 1;
            d_x[task][NH + s] = s_x[gg][NH + s];
        }
        __syncthreads();
        // ---- P5: pfc1 — v21 verbatim ----
        {
            const float* wrow = pfc1_W + (size_t)tid * 356;
            float bb = t_p1b[tid];
            for (int tt = 0; tt < CHc; ++tt) {
                float r0, r1;
                dot2f<89>(wrow, d_x[2*tt], d_x[2*tt+1], r0, r1);
                d_fch[2*tt][tid] = r0 + bb; d_fch[2*tt+1][tid] = r1 + bb;
            }
        }
        __syncthreads();
        // ---- P6: pfc2 — v21 verbatim ----
        {
            const float* wrow = pfc2_W + (size_t)j * 256;
            for (int tt = (tid >> 7); tt < CHc; tt += 2) {
                float r0, r1;
                dot2f<64>(wrow, d_fch[2*tt], d_fch[2*tt+1], r0, r1);
                d_fco[tt][0][j] = r0 + t_p2b[j];
                d_fco[tt][1][j] = r1 + t_p2b[j];
            }
        }
        __syncthreads();
        // ---- P7: q2 (ptr) — v21 verbatim ----
        {
            const float* col = ptr_W + (size_t)NH * NH + j;
            for (int tt = (tid >> 7); tt < CHc; tt += 2) {
                double qA0, qA1, qB0, qB1;
                qhalf(col, 0,  d_fco[tt][0], d_fco[tt][1], qA0, qA1);
                qhalf(col, 64, d_fco[tt][0], d_fco[tt][1], qB0, qB1);
                d_qh[tt][0][j] = dAbp[j] + (qA0 + qB0);
                d_qh[tt][1][j] = dAbp[j] + (qA1 + qB1);
            }
        }
        __syncthreads();
        // ---- P8: tanh heads — v21 verbatim ----
        for (int idx = tid; idx < 2 * CHc * NS; idx += NTHR) {
            int task = idx / NS, s = idx - task * NS;
            int tt = task >> 1, gg = task & 1;
            d_pl[task][s] = tanh_head(d_qh[tt][gg], dAp, t_vp, s_c0[gg][s], s_c1[gg][s]);
        }
        __syncthreads();
        // ---- P9: masked softmax2 + argmax + outputs — v21 verbatim ----
        {
            int w = tid >> 6;
            for (int task = w; task < 2 * CHc; task += 4) {
                int tt = task >> 1, gg = task & 1, tstep = t0 + tt;
                const unsigned* mwp = &maskb[tt][gg][0];
                bool u1 = (mwp[lane >> 5] >> (lane & 31)) & 1u;
                float l1 = d_pl[task][lane];
                float c1v = u1 ? l1 : NEGF;
                bool u2 = false; float l2 = 0.f, c2v = NEGF;
                if (lane + 64 < NS) {
                    u2 = (mwp[(lane + 64) >> 5] >> (lane & 31)) & 1u;
                    l2 = d_pl[task][lane + 64];
                    c2v = u2 ? l2 : NEGF;
                }
                float m = fmaxf(c1v, c2v);
                m = fmaxf(m, __shfl_xor(m, 32)); m = fmaxf(m, __shfl_xor(m, 16));
                m = fmaxf(m, __shfl_xor(m, 8));  m = fmaxf(m, __shfl_xor(m, 4));
                m = fmaxf(m, __shfl_xor(m, 2));  m = fmaxf(m, __shfl_xor(m, 1));
                float f1 = u1 ? (float)exp((double)l1 - (double)m) : 0.f;
                float f2 = (lane + 64 < NS && u2) ? (float)exp((double)l2 - (double)m) : 0.f;
                float bv = f1; int bi = lane;
                if (lane + 64 < NS && f2 > bv) { bv = f2; bi = lane + 64; }
                double ps = (double)f1 + (double)f2;
                #pragma unroll
                for (int o = 32; o >= 1; o >>= 1) {
                    float  ov = __shfl_xor(bv, o);
                    int    oi = __shfl_xor(bi, o);
                    double op = __shfl_xor(ps, o);
                    ps += op;
                    if (ov > bv || (ov == bv && oi < bi)) { bv = ov; bi = oi; }
                }
                int pt = s_sol2[gg][tstep];
                float a1s = __shfl(f1, pt & 63);
                float a2s = __shfl(f2, pt & 63);
                float a_pt = (pt < 64) ? a1s : a2s;
                if (lane == 0) {
                    int b2 = bbase + gg;
                    double logp = log((double)a_pt / ps);
                    out[OUT_TI + (size_t)b2 * NS + tstep]             = (float)bi;
                    out[OUT_LP + (size_t)b2 * (NS - 1) + (tstep - 1)] = (float)logp;
                }
            }
        }
        __syncthreads();
    }
}

extern "C" void kernel_launch(void* const* d_in, const int* in_sizes, int n_in,
                              void* d_out, int out_size, void* d_ws, size_t ws_size,
                              hipStream_t stream)
{
    (void)in_sizes; (void)n_in; (void)out_size; (void)d_ws; (void)ws_size;
    vae_v22<<<NBLK, NTHR, 0, stream>>>(
        (const float*)d_in[0], (const int*)d_in[1], (const int*)d_in[2], (const float*)d_in[3],
        (const float*)d_in[4], (const float*)d_in[5], (const float*)d_in[6], (const float*)d_in[7],
        (const float*)d_in[8], (const float*)d_in[9], (const float*)d_in[10], (const float*)d_in[11],
        (const float*)d_in[12], (const float*)d_in[13], (const float*)d_in[14], (const float*)d_in[15],
        (const float*)d_in[16], (const float*)d_in[17], (const float*)d_in[18], (const float*)d_in[19],
        (const float*)d_in[20], (const float*)d_in[21], (const float*)d_in[22], (const float*)d_in[23],
        (const float*)d_in[24], (const float*)d_in[25], (const float*)d_in[26], (const float*)d_in[27],
        (float*)d_out);
}

// Round 12
// 11635.398 us; speedup vs baseline: 1.5915x; 1.5915x over previous
//
#include <hip/hip_runtime.h>
#include <math.h>

static constexpr int NB  = 1024;
static constexpr int NS  = 100;
static constexpr int NH  = 128;
static constexpr int GPB = 2;           // batches per block
static constexpr int NTHR = 256;
static constexpr int NBLK = NB / GPB;   // 512 blocks, 2/CU
static constexpr int CH  = 4;           // chunk (timesteps per bulk)

static constexpr int OUT_MU = 0;
static constexpr int OUT_LV = NB * NS;
static constexpr int OUT_Z  = 2 * NB * NS;
static constexpr int OUT_TI = 3 * NB * NS;
static constexpr int OUT_LP = 4 * NB * NS;

#define NEGF (-3.4e38f)

// Fused 3-row x 2-batch f32 dot — per-accumulator fmaf chain k-ascending (v14 verbatim).
template<int C4>
__device__ __forceinline__ void dot2x3f(const float* __restrict__ wr0,
        const float* __restrict__ wr1, const float* __restrict__ wr2,
        const float* __restrict__ x0, const float* __restrict__ x1,
        float& r00, float& r01, float& r10, float& r11, float& r20, float& r21)
{
    const float4* W0 = reinterpret_cast<const float4*>(wr0);
    const float4* W1 = reinterpret_cast<const float4*>(wr1);
    const float4* W2 = reinterpret_cast<const float4*>(wr2);
    const float4* X0 = reinterpret_cast<const float4*>(x0);
    const float4* X1 = reinterpret_cast<const float4*>(x1);
    float a00 = 0.f, a01 = 0.f, a10 = 0.f, a11 = 0.f, a20 = 0.f, a21 = 0.f;
    #pragma unroll 4
    for (int c = 0; c < C4; ++c) {
        float4 u0 = W0[c], u1 = W1[c], u2 = W2[c];
        float4 v0 = X0[c], v1 = X1[c];
        a00 = fmaf(u0.x, v0.x, a00); a00 = fmaf(u0.y, v0.y, a00); a00 = fmaf(u0.z, v0.z, a00); a00 = fmaf(u0.w, v0.w, a00);
        a01 = fmaf(u0.x, v1.x, a01); a01 = fmaf(u0.y, v1.y, a01); a01 = fmaf(u0.z, v1.z, a01); a01 = fmaf(u0.w, v1.w, a01);
        a10 = fmaf(u1.x, v0.x, a10); a10 = fmaf(u1.y, v0.y, a10); a10 = fmaf(u1.z, v0.z, a10); a10 = fmaf(u1.w, v0.w, a10);
        a11 = fmaf(u1.x, v1.x, a11); a11 = fmaf(u1.y, v1.y, a11); a11 = fmaf(u1.z, v1.z, a11); a11 = fmaf(u1.w, v1.w, a11);
        a20 = fmaf(u2.x, v0.x, a20); a20 = fmaf(u2.y, v0.y, a20); a20 = fmaf(u2.z, v0.z, a20); a20 = fmaf(u2.w, v0.w, a20);
        a21 = fmaf(u2.x, v1.x, a21); a21 = fmaf(u2.y, v1.y, a21); a21 = fmaf(u2.z, v1.z, a21); a21 = fmaf(u2.w, v1.w, a21);
    }
    r00 = a00; r01 = a01; r10 = a10; r11 = a11; r20 = a20; r21 = a21;
}

// One weight row vs TWO LDS vectors — v14 verbatim per-accumulator chain.
template<int C4>
__device__ __forceinline__ void dot2f(const float* __restrict__ w,
        const float* __restrict__ x0, const float* __restrict__ x1, float& r0, float& r1)
{
    const float4* W = reinterpret_cast<const float4*>(w);
    const float4* X0 = reinterpret_cast<const float4*>(x0);
    const float4* X1 = reinterpret_cast<const float4*>(x1);
    float a0 = 0.f, a1 = 0.f;
    #pragma unroll 8
    for (int c = 0; c < C4; ++c) {
        float4 u = W[c];
        float4 v0 = X0[c], v1 = X1[c];
        a0 = fmaf(u.x, v0.x, a0); a0 = fmaf(u.y, v0.y, a0); a0 = fmaf(u.z, v0.z, a0); a0 = fmaf(u.w, v0.w, a0);
        a1 = fmaf(u.x, v1.x, a1); a1 = fmaf(u.y, v1.y, a1); a1 = fmaf(u.z, v1.z, a1); a1 = fmaf(u.w, v1.w, a1);
    }
    r0 = a0; r1 = a1;
}

// f64-accum dot (mu/lv epilogue) — R9 verbatim.
template<int C4>
__device__ __forceinline__ double dotwd(const float* __restrict__ w, const float* __restrict__ x)
{
    const float4* W = reinterpret_cast<const float4*>(w);
    double a = 0.0;
    #pragma unroll 8
    for (int c = 0; c < C4; ++c) {
        float4 u = W[c];
        const float* p = x + 4 * c;
        a = fma((double)u.x, (double)p[0], a);
        a = fma((double)u.y, (double)p[1], a);
        a = fma((double)u.z, (double)p[2], a);
        a = fma((double)u.w, (double)p[3], a);
    }
    return a;
}

// GRU nonlinearity (f64 internals, f32 storage) — R9 verbatim.
__device__ __forceinline__ void gruc(const float* __restrict__ bih, const float* __restrict__ bhh,
        const float* __restrict__ pa, const float* __restrict__ pb, float* __restrict__ h, int j)
{
    double r = 1.0 / (1.0 + exp(-(((double)pa[j]        + (double)bih[j])        + ((double)pb[j]        + (double)bhh[j]))));
    double z = 1.0 / (1.0 + exp(-(((double)pa[NH + j]   + (double)bih[NH + j])   + ((double)pb[NH + j]   + (double)bhh[NH + j]))));
    double n = tanh(((double)pa[2*NH + j] + (double)bih[2*NH + j]) + r * ((double)pb[2*NH + j] + (double)bhh[2*NH + j]));
    h[j] = (float)((1.0 - z) * n + z * (double)h[j]);
}

// q half-chain (v14-verbatim; HW-verified v19/v20/v21).
__device__ __forceinline__ void qhalf(const float* __restrict__ col, int k0,
        const float* __restrict__ hA, const float* __restrict__ hB, double& r0, double& r1)
{
    double a00=0.0,a01=0.0,a02=0.0,a03=0.0;
    double a10=0.0,a11=0.0,a12=0.0,a13=0.0;
    #pragma unroll 8
    for (int k = 0; k < 64; k += 4) {
        float w0 = col[(size_t)(k0+k+0) * NH];
        float w1 = col[(size_t)(k0+k+1) * NH];
        float w2 = col[(size_t)(k0+k+2) * NH];
        float w3 = col[(size_t)(k0+k+3) * NH];
        float4 h0 = *reinterpret_cast<const float4*>(&hA[k0+k]);
        float4 h1v = *reinterpret_cast<const float4*>(&hB[k0+k]);
        a00 = fma((double)w0, (double)h0.x, a00);
        a01 = fma((double)w1, (double)h0.y, a01);
        a02 = fma((double)w2, (double)h0.z, a02);
        a03 = fma((double)w3, (double)h0.w, a03);
        a10 = fma((double)w0, (double)h1v.x, a10);
        a11 = fma((double)w1, (double)h1v.y, a11);
        a12 = fma((double)w2, (double)h1v.z, a12);
        a13 = fma((double)w3, (double)h1v.w, a13);
    }
    r0 = (a00+a01)+(a02+a03); r1 = (a10+a11)+(a12+a13);
}

// relu head (v14-verbatim chain; HW-verified v19/v20/v21). qh pre-combined.
__device__ __forceinline__ float relu_head(const double* __restrict__ qh,
        const double2* __restrict__ dA, const float* __restrict__ va, float c0v, float c1v)
{
    double c00 = (double)c0v, c10 = (double)c1v;
    double acc0=0.0,acc1=0.0,acc2=0.0,acc3=0.0;
    #pragma unroll 4
    for (int h = 0; h < NH; h += 4) {
        double2 A0=dA[h+0],A1=dA[h+1],A2=dA[h+2],A3=dA[h+3];
        double p0 = fma(c00,A0.x,fma(c10,A0.y,qh[h+0]));
        double p1 = fma(c00,A1.x,fma(c10,A1.y,qh[h+1]));
        double p2 = fma(c00,A2.x,fma(c10,A2.y,qh[h+2]));
        double p3 = fma(c00,A3.x,fma(c10,A3.y,qh[h+3]));
        acc0 = fma(fmax(p0,0.0),(double)va[h+0],acc0);
        acc1 = fma(fmax(p1,0.0),(double)va[h+1],acc1);
        acc2 = fma(fmax(p2,0.0),(double)va[h+2],acc2);
        acc3 = fma(fmax(p3,0.0),(double)va[h+3],acc3);
    }
    return (float)((acc0+acc1)+(acc2+acc3));
}

// tanh head (v14-verbatim chain; HW-verified v19/v20/v21).
__device__ __forceinline__ float tanh_head(const double* __restrict__ qh,
        const double2* __restrict__ dA, const float* __restrict__ vp, float c0v, float c1v)
{
    double c00 = (double)c0v, c10 = (double)c1v;
    double acc0=0.0,acc1=0.0,acc2=0.0,acc3=0.0;
    #pragma unroll 4
    for (int h = 0; h < NH; h += 4) {
        double2 A0=dA[h+0],A1=dA[h+1],A2=dA[h+2],A3=dA[h+3];
        double p0 = fma(c00,A0.x,fma(c10,A0.y,qh[h+0]));
        double p1 = fma(c00,A1.x,fma(c10,A1.y,qh[h+1]));
        double p2 = fma(c00,A2.x,fma(c10,A2.y,qh[h+2]));
        double p3 = fma(c00,A3.x,fma(c10,A3.y,qh[h+3]));
        acc0 = fma((double)tanhf((float)p0),(double)vp[h+0],acc0);
        acc1 = fma((double)tanhf((float)p1),(double)vp[h+1],acc1);
        acc2 = fma((double)tanhf((float)p2),(double)vp[h+2],acc2);
        acc3 = fma((double)tanhf((float)p3),(double)vp[h+3],acc3);
    }
    return (float)((acc0+acc1)+(acc2+acc3));
}

// context chain (v14-verbatim; HW-verified v19/v20/v21).
__device__ __forceinline__ float ctx_chain(const float* __restrict__ a,
        const float* __restrict__ c0, const float* __restrict__ c1,
        float w0, float w1, float bb)
{
    double a0=0.0,a1=0.0,a2=0.0,a3=0.0;
    #pragma unroll 5
    for (int s = 0; s < NS; s += 4) {
        float ih0 = fmaf(c0[s+0], w0, fmaf(c1[s+0], w1, bb));
        float ih1 = fmaf(c0[s+1], w0, fmaf(c1[s+1], w1, bb));
        float ih2 = fmaf(c0[s+2], w0, fmaf(c1[s+2], w1, bb));
        float ih3 = fmaf(c0[s+3], w0, fmaf(c1[s+3], w1, bb));
        a0 += (double)a[s+0] * (double)ih0;
        a1 += (double)a[s+1] * (double)ih1;
        a2 += (double)a[s+2] * (double)ih2;
        a3 += (double)a[s+3] * (double)ih3;
    }
    return (float)((a0+a1)+(a2+a3));
}

__global__ __launch_bounds__(NTHR) void vae_v23(
    const float* __restrict__ instance, const int* __restrict__ sol1,
    const int* __restrict__ sol2, const float* __restrict__ eps,
    const float* __restrict__ emb_i_W, const float* __restrict__ emb_i_b,
    const float* __restrict__ emb_r_W, const float* __restrict__ emb_r_b,
    const float* __restrict__ attn_W, const float* __restrict__ attn_v,
    const float* __restrict__ gru_Wih, const float* __restrict__ gru_Whh,
    const float* __restrict__ gru_bih, const float* __restrict__ gru_bhh,
    const float* __restrict__ grud_Wih, const float* __restrict__ grud_Whh,
    const float* __restrict__ grud_bih, const float* __restrict__ grud_bhh,
    const float* __restrict__ efc1_W, const float* __restrict__ efc1_b,
    const float* __restrict__ efc2_W, const float* __restrict__ efc2_b,
    const float* __restrict__ ptr_W, const float* __restrict__ ptr_v,
    const float* __restrict__ pfc1_W, const float* __restrict__ pfc1_b,
    const float* __restrict__ pfc2_W, const float* __restrict__ pfc2_b,
    float* __restrict__ out)
{
    __shared__ __align__(16) float  s_x[GPB][360];          // Z kept at [128..227] for decoder
    __shared__ __align__(16) float  s_h1[GPB][NH], s_h2[GPB][NH];
    __shared__ float  s_pa[GPB][3 * NH], s_pb[GPB][3 * NH];
    __shared__ double2 dAa[NH], dAp[NH];
    __shared__ double dAba[NH], dAbp[NH];
    __shared__ float  s_c0[GPB][NS], s_c1[GPB][NS];
    __shared__ float  t_wi0[NH], t_wi1[NH], t_bi[NH];
    __shared__ float  t_wr0[NH], t_wr1[NH], t_br[NH];
    __shared__ float  t_va[NH], t_vp[NH];
    __shared__ float  t_gbih[3*NH], t_gbhh[3*NH], t_dbih[3*NH], t_dbhh[3*NH];
    __shared__ float  t_p1b[256], t_p2b[NH];
    __shared__ int    s_sol1[GPB][NS], s_sol2[GPB][NS];
    // ---- chunk scratch (shared by encoder and decoder bulk) ----
    __shared__ __align__(16) float  s_ref[GPB][NH];
    __shared__ __align__(16) float  h1buf[CH][GPB][NH];
    __shared__ float    rcb0[GPB][CH+1], rcb1[GPB][CH+1];
    __shared__ unsigned maskb[CH][GPB][4], m_run[GPB][4];
    __shared__ __align__(16) double d_qh[CH][GPB][NH];
    __shared__ __align__(16) float  d_pl[2*CH][NS];
    __shared__ __align__(16) float  d_x[2*CH][360];
    __shared__ __align__(16) float  d_fch[2*CH][256];
    __shared__ __align__(16) float  d_fco[CH][GPB][NH];

    const int tid = threadIdx.x;
    const int bbase = blockIdx.x * GPB;
    const int j = tid & (NH - 1);
    const int half = tid >> 7;
    const int g = half;
    const int lane = tid & 63;

    // ---------- init (v14 verbatim) ----------
    if (tid < NH) {
        t_wi0[tid] = emb_i_W[2*tid]; t_wi1[tid] = emb_i_W[2*tid+1]; t_bi[tid] = emb_i_b[tid];
        t_wr0[tid] = emb_r_W[2*tid]; t_wr1[tid] = emb_r_W[2*tid+1]; t_br[tid] = emb_r_b[tid];
        t_va[tid] = attn_v[tid]; t_vp[tid] = ptr_v[tid];
        t_p2b[tid] = pfc2_b[tid];
    }
    t_p1b[tid] = pfc1_b[tid];
    for (int i = tid; i < 3 * NH; i += NTHR) {
        t_gbih[i] = gru_bih[i]; t_gbhh[i] = gru_bhh[i];
        t_dbih[i] = grud_bih[i]; t_dbhh[i] = grud_bhh[i];
    }
    for (int i = tid; i < GPB * NS; i += NTHR) {
        int gg = i / NS, s = i - gg * NS;
        s_c0[gg][s] = instance[(size_t)((bbase + gg) * NS + s) * 2 + 0];
        s_c1[gg][s] = instance[(size_t)((bbase + gg) * NS + s) * 2 + 1];
        s_sol1[gg][s] = sol1[(bbase + gg) * NS + s];
        s_sol2[gg][s] = sol2[(bbase + gg) * NS + s];
    }
    s_h1[g][j] = 0.f;
    s_h2[g][j] = 0.f;
    __syncthreads();
    {   // collapse tables (R9 verbatim)
        const float* Wm = (half == 0) ? attn_W : ptr_W;
        double a0 = 0.0, a1 = 0.0, ab = 0.0;
        for (int k = 0; k < NH; ++k) {
            double wv2 = (double)Wm[(size_t)k * NH + j];
            a0 = fma((double)t_wi0[k], wv2, a0);
            a1 = fma((double)t_wi1[k], wv2, a1);
            ab = fma((double)t_bi[k],  wv2, ab);
        }
        if (half == 0) { dAa[j].x = a0; dAa[j].y = a1; dAba[j] = ab; }
        else           { dAp[j].x = a0; dAp[j].y = a1; dAbp[j] = ab; }
    }
    {   // initial encoder ref (sol1[0])
        int sp = s_sol1[g][0];
        s_ref[g][j] = fmaf(s_c0[g][sp], t_wr0[j], fmaf(s_c1[g][sp], t_wr1[j], t_br[j]));
    }
    __syncthreads();

    // ---------- encoder: chunked h1-serial + bulk heads + h2-serial ----------
    for (int c = 0; c < (NS - 1 + CH - 1) / CH; ++c) {
        const int t0 = 1 + c * CH;
        const int CHc = (t0 + CH <= NS) ? CH : (NS - t0);
        if (tid < GPB) {    // pre: enc ref coords from sol1 (data-independent)
            const int gg = tid;
            for (int qi = 0; qi < CHc; ++qi) {
                int sp = s_sol1[gg][t0 + qi];
                rcb0[gg][qi] = s_c0[gg][sp];
                rcb1[gg][qi] = s_c1[gg][sp];
            }
        }
        __syncthreads();
        // ---- E1: h1 serial (v14 PH1/PH2 chains; v15-D1 pattern) ----
        for (int q = 0; q < CHc; ++q) {
            if (half == 0) {
                float a00,a01,a10,a11,a20,a21;
                dot2x3f<32>(gru_Wih + (size_t)j * NH, gru_Wih + (size_t)(NH + j) * NH,
                            gru_Wih + (size_t)(2*NH + j) * NH, s_ref[0], s_ref[1],
                            a00,a01,a10,a11,a20,a21);
                s_pa[0][j] = a00;        s_pa[1][j] = a01;
                s_pa[0][NH + j] = a10;   s_pa[1][NH + j] = a11;
                s_pa[0][2*NH + j] = a20; s_pa[1][2*NH + j] = a21;
            } else {
                float a00,a01,a10,a11,a20,a21;
                dot2x3f<32>(gru_Whh + (size_t)j * NH, gru_Whh + (size_t)(NH + j) * NH,
                            gru_Whh + (size_t)(2*NH + j) * NH, s_h1[0], s_h1[1],
                            a00,a01,a10,a11,a20,a21);
                s_pb[0][j] = a00;        s_pb[1][j] = a01;
                s_pb[0][NH + j] = a10;   s_pb[1][NH + j] = a11;
                s_pb[0][2*NH + j] = a20; s_pb[1][2*NH + j] = a21;
            }
            __syncthreads();
            gruc(t_gbih, t_gbhh, s_pa[g], s_pb[g], s_h1[g], j);
            h1buf[q][g][j] = s_h1[g][j];
            // next step's x-input ref = emb_r(sol1[t0+q])
            s_ref[g][j] = fmaf(rcb0[g][q], t_wr0[j], fmaf(rcb1[g][q], t_wr1[j], t_br[j]));
            __syncthreads();
        }
        // ---- P1: q (attn) bulk — v20-P1 verbatim on h1buf ----
        {
            const float* col = attn_W + (size_t)NH * NH + j;
            for (int tt = (tid >> 7); tt < CHc; tt += 2) {
                double qA0, qA1, qB0, qB1;
                qhalf(col, 0,  h1buf[tt][0], h1buf[tt][1], qA0, qA1);
                qhalf(col, 64, h1buf[tt][0], h1buf[tt][1], qB0, qB1);
                d_qh[tt][0][j] = dAba[j] + (qA0 + qB0);
                d_qh[tt][1][j] = dAba[j] + (qA1 + qB1);
            }
        }
        __syncthreads();
        // ---- P2: relu heads bulk — v20-P2 verbatim ----
        for (int idx = tid; idx < 2 * CHc * NS; idx += NTHR) {
            int task = idx / NS, s = idx - task * NS;
            int tt = task >> 1, gg = task & 1;
            d_pl[task][s] = relu_head(d_qh[tt][gg], dAa, t_va, s_c0[gg][s], s_c1[gg][s]);
        }
        __syncthreads();
        // ---- P3: softmax1 bulk, one wave per task — v20-P3 verbatim ----
        {
            int w = tid >> 6;
            for (int task = w; task < 2 * CHc; task += 4) {
                float v1 = d_pl[task][lane];
                bool hasHi = (lane + 64 < NS);
                float v2 = hasHi ? d_pl[task][lane + 64] : NEGF;
                float m = fmaxf(v1, v2);
                m = fmaxf(m, __shfl_xor(m, 32)); m = fmaxf(m, __shfl_xor(m, 16));
                m = fmaxf(m, __shfl_xor(m, 8));  m = fmaxf(m, __shfl_xor(m, 4));
                m = fmaxf(m, __shfl_xor(m, 2));  m = fmaxf(m, __shfl_xor(m, 1));
                float f1 = (float)exp((double)v1 - (double)m);
                float f2 = 0.f;
                if (hasHi) f2 = (float)exp((double)v2 - (double)m);
                double ps = (double)f1 + (double)f2;
                ps += __shfl_xor(ps, 32); ps += __shfl_xor(ps, 16);
                ps += __shfl_xor(ps, 8);  ps += __shfl_xor(ps, 4);
                ps += __shfl_xor(ps, 2);  ps += __shfl_xor(ps, 1);
                d_pl[task][lane] = (float)((double)f1 / ps);
                if (hasHi) d_pl[task][lane + 64] = (float)((double)f2 / ps);
            }
        }
        __syncthreads();
        // ---- P4: ctx + new-ref into d_x ([ref_new | ctx] layout = v14 s_x) ----
        for (int idx = tid; idx < 2 * CHc * NH; idx += NTHR) {
            int task = idx >> 7, jj = idx & 127;
            int tt = task >> 1, gg = task & 1;
            d_x[task][NH + jj] = ctx_chain(d_pl[task], s_c0[gg], s_c1[gg], t_wi0[jj], t_wi1[jj], t_bi[jj]);
            d_x[task][jj] = fmaf(rcb0[gg][tt], t_wr0[jj], fmaf(rcb1[gg][tt], t_wr1[jj], t_br[jj]));
        }
        __syncthreads();
        // ---- E2: h2 serial — v14's GRUd dots+gruc2 phases, x from d_x ----
        for (int q = 0; q < CHc; ++q) {
            if (half == 0) {    // x-side (v14 verbatim chains)
                float a00,a01,a10,a11,a20,a21;
                dot2x3f<64>(grud_Wih + (size_t)j * 256, grud_Wih + (size_t)(NH + j) * 256,
                            grud_Wih + (size_t)(2*NH + j) * 256, d_x[2*q], d_x[2*q+1],
                            a00,a01,a10,a11,a20,a21);
                s_pa[0][j] = a00;        s_pa[1][j] = a01;
                s_pa[0][NH + j] = a10;   s_pa[1][NH + j] = a11;
                s_pa[0][2*NH + j] = a20; s_pa[1][2*NH + j] = a21;
            } else {            // h-side (v14 verbatim chains)
                float a00,a01,a10,a11,a20,a21;
                dot2x3f<32>(grud_Whh + (size_t)j * NH, grud_Whh + (size_t)(NH + j) * NH,
                            grud_Whh + (size_t)(2*NH + j) * NH, s_h2[0], s_h2[1],
                            a00,a01,a10,a11,a20,a21);
                s_pb[0][j] = a00;        s_pb[1][j] = a01;
                s_pb[0][NH + j] = a10;   s_pb[1][NH + j] = a11;
                s_pb[0][2*NH + j] = a20; s_pb[1][2*NH + j] = a21;
            }
            __syncthreads();
            gruc(t_dbih, t_dbhh, s_pa[g], s_pb[g], s_h2[g], j);
            __syncthreads();
        }
    }

    // ---------- epilogue: mu, lv, Z (R9 verbatim) ----------
    for (int idx = tid; idx < GPB * NS; idx += NTHR) {
        int gg = idx / NS, s = idx - gg * NS, b = bbase + gg;
        double mu = dotwd<32>(efc1_W + (size_t)s * NH, s_h2[gg]) + (double)efc1_b[s];
        double lv = dotwd<32>(efc2_W + (size_t)s * NH, s_h2[gg]) + (double)efc2_b[s];
        double z  = mu + (double)eps[(size_t)b * NS + s] * exp(0.5 * lv);
        out[OUT_MU + b * NS + s] = (float)mu;
        out[OUT_LV + b * NS + s] = (float)lv;
        out[OUT_Z  + b * NS + s] = (float)z;
        s_x[gg][NH + s] = (float)z;   // Z slot [128..227], preserved through decoder
    }
    s_h1[g][j] = 0.f;
    __syncthreads();
    if (tid < GPB) {   // mask bitmap init (v15-verified) + TI[0]
        int b = bbase + tid;
        int s0 = s_sol2[tid][0];
        m_run[tid][0] = 0xFFFFFFFFu; m_run[tid][1] = 0xFFFFFFFFu;
        m_run[tid][2] = 0xFFFFFFFFu; m_run[tid][3] = 0xFu;
        m_run[tid][s0 >> 5] &= ~(1u << (s0 & 31));
        out[OUT_TI + b * NS + 0] = (float)s0;
    }
    __syncthreads();
    {   // initial decoder ref
        int p0 = s_sol2[g][0];
        s_ref[g][j] = fmaf(s_c0[g][p0], t_wr0[j], fmaf(s_c1[g][p0], t_wr1[j], t_br[j]));
    }
    __syncthreads();

    // ---------- decoder (v20 verbatim) ----------
    for (int c = 0; c < (NS - 1 + CH - 1) / CH; ++c) {
        const int t0 = 1 + c * CH;
        const int CHc = (t0 + CH <= NS) ? CH : (NS - t0);
        if (tid < GPB) {    // pre-phase: mask snapshots + ref coords (v15-verified)
            const int gg = tid;
            for (int qi = 0; qi <= CHc; ++qi) {
                int tt = t0 + qi;
                if (qi < CHc) {
                    maskb[qi][gg][0] = m_run[gg][0];
                    maskb[qi][gg][1] = m_run[gg][1];
                    maskb[qi][gg][2] = m_run[gg][2];
                    maskb[qi][gg][3] = m_run[gg][3];
                    int pt = s_sol2[gg][tt];
                    m_run[gg][pt >> 5] &= ~(1u << (pt & 31));
                }
                int sp = s_sol2[gg][tt - 1];
                rcb0[gg][qi] = s_c0[gg][sp];
                rcb1[gg][qi] = s_c1[gg][sp];
            }
        }
        __syncthreads();
        // ---- D1: serial GRU1 recurrence (v15-verified) ----
        for (int q = 0; q < CHc; ++q) {
            if (half == 0) {
                float a00,a01,a10,a11,a20,a21;
                dot2x3f<32>(gru_Wih + (size_t)j * NH, gru_Wih + (size_t)(NH + j) * NH,
                            gru_Wih + (size_t)(2*NH + j) * NH, s_ref[0], s_ref[1],
                            a00,a01,a10,a11,a20,a21);
                s_pa[0][j] = a00;        s_pa[1][j] = a01;
                s_pa[0][NH + j] = a10;   s_pa[1][NH + j] = a11;
                s_pa[0][2*NH + j] = a20; s_pa[1][2*NH + j] = a21;
            } else {
                float a00,a01,a10,a11,a20,a21;
                dot2x3f<32>(gru_Whh + (size_t)j * NH, gru_Whh + (size_t)(NH + j) * NH,
                            gru_Whh + (size_t)(2*NH + j) * NH, s_h1[0], s_h1[1],
                            a00,a01,a10,a11,a20,a21);
                s_pb[0][j] = a00;        s_pb[1][j] = a01;
                s_pb[0][NH + j] = a10;   s_pb[1][NH + j] = a11;
                s_pb[0][2*NH + j] = a20; s_pb[1][2*NH + j] = a21;
            }
            __syncthreads();
            gruc(t_gbih, t_gbhh, s_pa[g], s_pb[g], s_h1[g], j);
            h1buf[q][g][j] = s_h1[g][j];
            s_ref[g][j] = fmaf(rcb0[g][q+1], t_wr0[j], fmaf(rcb1[g][q+1], t_wr1[j], t_br[j]));
            __syncthreads();
        }
        // ---- P1: q (attn) — v20 verbatim ----
        {
            const float* col = attn_W + (size_t)NH * NH + j;
            for (int tt = (tid >> 7); tt < CHc; tt += 2) {
                double qA0, qA1, qB0, qB1;
                qhalf(col, 0,  h1buf[tt][0], h1buf[tt][1], qA0, qA1);
                qhalf(col, 64, h1buf[tt][0], h1buf[tt][1], qB0, qB1);
                d_qh[tt][0][j] = dAba[j] + (qA0 + qB0);
                d_qh[tt][1][j] = dAba[j] + (qA1 + qB1);
            }
        }
        __syncthreads();
        // ---- P2: relu heads — v20 verbatim ----
        for (int idx = tid; idx < 2 * CHc * NS; idx += NTHR) {
            int task = idx / NS, s = idx - task * NS;
            int tt = task >> 1, gg = task & 1;
            d_pl[task][s] = relu_head(d_qh[tt][gg], dAa, t_va, s_c0[gg][s], s_c1[gg][s]);
        }
        __syncthreads();
        // ---- P3: softmax1 — v20 verbatim ----
        {
            int w = tid >> 6;
            for (int task = w; task < 2 * CHc; task += 4) {
                float v1 = d_pl[task][lane];
                bool hasHi = (lane + 64 < NS);
                float v2 = hasHi ? d_pl[task][lane + 64] : NEGF;
                float m = fmaxf(v1, v2);
                m = fmaxf(m, __shfl_xor(m, 32)); m = fmaxf(m, __shfl_xor(m, 16));
                m = fmaxf(m, __shfl_xor(m, 8));  m = fmaxf(m, __shfl_xor(m, 4));
                m = fmaxf(m, __shfl_xor(m, 2));  m = fmaxf(m, __shfl_xor(m, 1));
                float f1 = (float)exp((double)v1 - (double)m);
                float f2 = 0.f;
                if (hasHi) f2 = (float)exp((double)v2 - (double)m);
                double ps = (double)f1 + (double)f2;
                ps += __shfl_xor(ps, 32); ps += __shfl_xor(ps, 16);
                ps += __shfl_xor(ps, 8);  ps += __shfl_xor(ps, 4);
                ps += __shfl_xor(ps, 2);  ps += __shfl_xor(ps, 1);
                d_pl[task][lane] = (float)((double)f1 / ps);
                if (hasHi) d_pl[task][lane + 64] = (float)((double)f2 / ps);
            }
        }
        __syncthreads();
        // ---- P4: context + Z copy + ref into d_x — v20 verbatim ----
        for (int idx = tid; idx < 2 * CHc * NH; idx += NTHR) {
            int task = idx >> 7, jj = idx & 127;
            int tt = task >> 1, gg = task & 1;
            d_x[task][jj] = ctx_chain(d_pl[task], s_c0[gg], s_c1[gg], t_wi0[jj], t_wi1[jj], t_bi[jj]);
            float rc0 = rcb0[gg][tt], rc1 = rcb1[gg][tt];
            d_x[task][228 + jj] = fmaf(rc0, t_wr0[jj], fmaf(rc1, t_wr1[jj], t_br[jj]));
        }
        for (int idx = tid; idx < 2 * CHc * NS; idx += NTHR) {
            int task = idx / NS, s = idx - task * NS;
            int gg = task & 1;
            d_x[task][NH + s] = s_x[gg][NH + s];
        }
        __syncthreads();
        // ---- P5: pfc1 — v20 verbatim ----
        {
            const float* wrow = pfc1_W + (size_t)tid * 356;
            float bb = t_p1b[tid];
            for (int tt = 0; tt < CHc; ++tt) {
                float r0, r1;
                dot2f<89>(wrow, d_x[2*tt], d_x[2*tt+1], r0, r1);
                d_fch[2*tt][tid] = r0 + bb; d_fch[2*tt+1][tid] = r1 + bb;
            }
        }
        __syncthreads();
        // ---- P6: pfc2 — v20 verbatim ----
        {
            const float* wrow = pfc2_W + (size_t)j * 256;
            for (int tt = (tid >> 7); tt < CHc; tt += 2) {
                float r0, r1;
                dot2f<64>(wrow, d_fch[2*tt], d_fch[2*tt+1], r0, r1);
                d_fco[tt][0][j] = r0 + t_p2b[j];
                d_fco[tt][1][j] = r1 + t_p2b[j];
            }
        }
        __syncthreads();
        // ---- P7: q2 (ptr) — v20 verbatim ----
        {
            const float* col = ptr_W + (size_t)NH * NH + j;
            for (int tt = (tid >> 7); tt < CHc; tt += 2) {
                double qA0, qA1, qB0, qB1;
                qhalf(col, 0,  d_fco[tt][0], d_fco[tt][1], qA0, qA1);
                qhalf(col, 64, d_fco[tt][0], d_fco[tt][1], qB0, qB1);
                d_qh[tt][0][j] = dAbp[j] + (qA0 + qB0);
                d_qh[tt][1][j] = dAbp[j] + (qA1 + qB1);
            }
        }
        __syncthreads();
        // ---- P8: tanh heads — v20 verbatim ----
        for (int idx = tid; idx < 2 * CHc * NS; idx += NTHR) {
            int task = idx / NS, s = idx - task * NS;
            int tt = task >> 1, gg = task & 1;
            d_pl[task][s] = tanh_head(d_qh[tt][gg], dAp, t_vp, s_c0[gg][s], s_c1[gg][s]);
        }
        __syncthreads();
        // ---- P9: masked softmax2 + argmax + outputs — v20 verbatim ----
        {
            int w = tid >> 6;
            for (int task = w; task < 2 * CHc; task += 4) {
                int tt = task >> 1, gg = task & 1, tstep = t0 + tt;
                const unsigned* mwp = &maskb[tt][gg][0];
                bool u1 = (mwp[lane >> 5] >> (lane & 31)) & 1u;
                float l1 = d_pl[task][lane];
                float c1v = u1 ? l1 : NEGF;
                bool u2 = false; float l2 = 0.f, c2v = NEGF;
                if (lane + 64 < NS) {
                    u2 = (mwp[(lane + 64) >> 5] >> (lane & 31)) & 1u;
                    l2 = d_pl[task][lane + 64];
                    c2v = u2 ? l2 : NEGF;
                }
                float m = fmaxf(c1v, c2v);
                m = fmaxf(m, __shfl_xor(m, 32)); m = fmaxf(m, __shfl_xor(m, 16));
                m = fmaxf(m, __shfl_xor(m, 8));  m = fmaxf(m, __shfl_xor(m, 4));
                m = fmaxf(m, __shfl_xor(m, 2));  m = fmaxf(m, __shfl_xor(m, 1));
                float f1 = u1 ? (float)exp((double)l1 - (double)m) : 0.f;
                float f2 = (lane + 64 < NS && u2) ? (float)exp((double)l2 - (double)m) : 0.f;
                float bv = f1; int bi = lane;
                if (lane + 64 < NS && f2 > bv) { bv = f2; bi = lane + 64; }
                double ps = (double)f1 + (double)f2;
                #pragma unroll
                for (int o = 32; o >= 1; o >>= 1) {
                    float  ov = __shfl_xor(bv, o);
                    int    oi = __shfl_xor(bi, o);
                    double op = __shfl_xor(ps, o);
                    ps += op;
                    if (ov > bv || (ov == bv && oi < bi)) { bv = ov; bi = oi; }
                }
                int pt = s_sol2[gg][tstep];
                float a1s = __shfl(f1, pt & 63);
                float a2s = __shfl(f2, pt & 63);
                float a_pt = (pt < 64) ? a1s : a2s;
                if (lane == 0) {
                    int b2 = bbase + gg;
                    double logp = log((double)a_pt / ps);
                    out[OUT_TI + (size_t)b2 * NS + tstep]             = (float)bi;
                    out[OUT_LP + (size_t)b2 * (NS - 1) + (tstep - 1)] = (float)logp;
                }
            }
        }
        __syncthreads();
    }
}

extern "C" void kernel_launch(void* const* d_in, const int* in_sizes, int n_in,
                              void* d_out, int out_size, void* d_ws, size_t ws_size,
                              hipStream_t stream)
{
    (void)in_sizes; (void)n_in; (void)out_size; (void)d_ws; (void)ws_size;
    vae_v23<<<NBLK, NTHR, 0, stream>>>(
        (const float*)d_in[0], (const int*)d_in[1], (const int*)d_in[2], (const float*)d_in[3],
        (const float*)d_in[4], (const float*)d_in[5], (const float*)d_in[6], (const float*)d_in[7],
        (const float*)d_in[8], (const float*)d_in[9], (const float*)d_in[10], (const float*)d_in[11],
        (const float*)d_in[12], (const float*)d_in[13], (const float*)d_in[14], (const float*)d_in[15],
        (const float*)d_in[16], (const float*)d_in[17], (const float*)d_in[18], (const float*)d_in[19],
        (const float*)d_in[20], (const float*)d_in[21], (const float*)d_in[22], (const float*)d_in[23],
        (const float*)d_in[24], (const float*)d_in[25], (const float*)d_in[26], (const float*)d_in[27],
        (float*)d_out);
}